// Round 1
// baseline (482.800 us; speedup 1.0000x reference)
//
#include <hip/hip_runtime.h>
#include <hip/hip_bf16.h>

typedef unsigned short u16;
typedef u16 u16x8 __attribute__((ext_vector_type(8)));
typedef u16 u16x4 __attribute__((ext_vector_type(4)));
typedef __bf16 bf16x8 __attribute__((ext_vector_type(8)));
typedef float f32x4 __attribute__((ext_vector_type(4)));

__device__ __forceinline__ u16 f2bf(float f) {
  union { __hip_bfloat16 h; u16 u; } cv;
  cv.h = __float2bfloat16(f);
  return cv.u;
}

__device__ __forceinline__ void glds16(const void* g, void* l) {
  __builtin_amdgcn_global_load_lds(
      (const __attribute__((address_space(1))) unsigned int*)g,
      (__attribute__((address_space(3))) unsigned int*)l, 16, 0, 0);
}

// ---------------- transpose + fp32->bf16 convert:  W[K][N] -> Wt[N][K] ----------------
__global__ __launch_bounds__(256) void transpose_bf16(const float* __restrict__ W,
                                                      u16* __restrict__ Wt,
                                                      int K, int N) {
  __shared__ float tile[32][33];
  int tx = threadIdx.x, ty = threadIdx.y;
  int n0 = blockIdx.x * 32, k0 = blockIdx.y * 32;
#pragma unroll
  for (int j = 0; j < 4; ++j)
    tile[ty + j * 8][tx] = W[(size_t)(k0 + ty + j * 8) * N + n0 + tx];
  __syncthreads();
#pragma unroll
  for (int j = 0; j < 4; ++j)
    Wt[(size_t)(n0 + ty + j * 8) * K + k0 + tx] = f2bf(tile[tx][ty + j * 8]);
}

// ---------------- LayerNorm: fp32 in [rows][1024] -> bf16 out ----------------
__global__ __launch_bounds__(256) void ln_kernel(const float* __restrict__ x,
                                                 const float* __restrict__ w,
                                                 const float* __restrict__ b,
                                                 u16* __restrict__ out) {
  int row = blockIdx.x, t = threadIdx.x;
  const float* xr = x + (size_t)row * 1024;
  float4 v = *reinterpret_cast<const float4*>(xr + t * 4);
  float s = v.x + v.y + v.z + v.w;
  float s2 = v.x * v.x + v.y * v.y + v.z * v.z + v.w * v.w;
#pragma unroll
  for (int m = 1; m < 64; m <<= 1) {
    s += __shfl_xor(s, m, 64);
    s2 += __shfl_xor(s2, m, 64);
  }
  __shared__ float red[8];
  if ((t & 63) == 0) { red[t >> 6] = s; red[(t >> 6) + 4] = s2; }
  __syncthreads();
  s = red[0] + red[1] + red[2] + red[3];
  s2 = red[4] + red[5] + red[6] + red[7];
  float mu = s * (1.f / 1024.f);
  float var = s2 * (1.f / 1024.f) - mu * mu;
  float rs = rsqrtf(var + 1e-5f);
  float4 wv = *reinterpret_cast<const float4*>(w + t * 4);
  float4 bv = *reinterpret_cast<const float4*>(b + t * 4);
  u16x4 o;
  o.x = f2bf((v.x - mu) * rs * wv.x + bv.x);
  o.y = f2bf((v.y - mu) * rs * wv.y + bv.y);
  o.z = f2bf((v.z - mu) * rs * wv.z + bv.z);
  o.w = f2bf((v.w - mu) * rs * wv.w + bv.w);
  *reinterpret_cast<u16x4*>(out + (size_t)row * 1024 + t * 4) = o;
}

// ---------------- MFMA GEMM: C[M,N] = A[M,K] @ Bt[N,K]^T (+epilogue) ----------------
// MODE 0: QKV scatter -> q/k/v [B,H,N,Dh] bf16, scale applied to q part
// MODE 1: fp32 out = acc + bias + res
// MODE 2: bf16 out = gelu_exact(acc + bias)
template <int MODE>
__global__ __launch_bounds__(256) void gemm128(
    const u16* __restrict__ A, const u16* __restrict__ Bt,
    const float* __restrict__ b0, const float* __restrict__ b1,
    const float* __restrict__ b2, const float* __restrict__ res,
    u16* __restrict__ o0, u16* __restrict__ o1, u16* __restrict__ o2,
    float* __restrict__ of, int M, int N, int K, float qscale) {
  __shared__ u16 As[128 * 32];
  __shared__ u16 Bs[128 * 32];
  const int tid = threadIdx.x;
  const int lane = tid & 63, w = tid >> 6;
  const int wr = w >> 1, wc = w & 1;
  const int l15 = lane & 15, l4 = lane >> 4;
  const int row0 = blockIdx.x * 128, col0 = blockIdx.y * 128;
  f32x4 acc[4][4];
#pragma unroll
  for (int m = 0; m < 4; ++m)
#pragma unroll
    for (int n = 0; n < 4; ++n) acc[m][n] = (f32x4){0.f, 0.f, 0.f, 0.f};

  for (int k0 = 0; k0 < K; k0 += 32) {
    __syncthreads();
#pragma unroll
    for (int i = 0; i < 2; ++i) {
      int c = i * 256 + tid;
      glds16(A + (size_t)(row0 + (c >> 2)) * K + k0 + (c & 3) * 8, &As[c * 8]);
      glds16(Bt + (size_t)(col0 + (c >> 2)) * K + k0 + (c & 3) * 8, &Bs[c * 8]);
    }
    __syncthreads();
    bf16x8 af[4], bfr[4];
#pragma unroll
    for (int m = 0; m < 4; ++m)
      af[m] = *reinterpret_cast<const bf16x8*>(&As[(wr * 64 + m * 16 + l15) * 32 + l4 * 8]);
#pragma unroll
    for (int n = 0; n < 4; ++n)
      bfr[n] = *reinterpret_cast<const bf16x8*>(&Bs[(wc * 64 + n * 16 + l15) * 32 + l4 * 8]);
#pragma unroll
    for (int m = 0; m < 4; ++m)
#pragma unroll
      for (int n = 0; n < 4; ++n)
        acc[m][n] = __builtin_amdgcn_mfma_f32_16x16x32_bf16(af[m], bfr[n], acc[m][n], 0, 0, 0);
  }

#pragma unroll
  for (int m = 0; m < 4; ++m)
#pragma unroll
    for (int n = 0; n < 4; ++n)
#pragma unroll
      for (int r = 0; r < 4; ++r) {
        int row = row0 + wr * 64 + m * 16 + l4 * 4 + r;
        int col = col0 + wc * 64 + n * 16 + l15;
        float val = acc[m][n][r];
        if constexpr (MODE == 0) {
          int which = col >> 10, cc = col & 1023;
          val += (which == 0 ? b0 : which == 1 ? b1 : b2)[cc];
          if (which == 0) val *= qscale;
          u16* dst = which == 0 ? o0 : which == 1 ? o1 : o2;
          dst[(((size_t)(row >> 10) * 16 + (cc >> 6)) * 1024 + (row & 1023)) * 64 + (cc & 63)] =
              f2bf(val);
        } else if constexpr (MODE == 1) {
          of[(size_t)row * N + col] = val + b0[col] + res[(size_t)row * N + col];
        } else {
          val += b0[col];
          float g = 0.5f * val * (1.0f + erff(val * 0.70710678118f));
          o0[(size_t)row * N + col] = f2bf(g);
        }
      }
}

// ---------------- fused flash attention: q,k,v [BH, N, 64] bf16 (q pre-scaled) ----------------
// out o in [B, N, D=1024] bf16 layout for the Wo GEMM
__global__ __launch_bounds__(256) void attn_kernel(const u16* __restrict__ q,
                                                   const u16* __restrict__ k,
                                                   const u16* __restrict__ v,
                                                   u16* __restrict__ o) {
  const int bh = blockIdx.x, qb = blockIdx.y;
  const int b = bh >> 4, h = bh & 15;
  __shared__ u16 Qs[64 * 64];
  __shared__ u16 Ks[32 * 64];
  __shared__ u16 Vt[64 * 32];
  __shared__ u16 Ps[4][16 * 32];
  const int tid = threadIdx.x, lane = tid & 63, w = tid >> 6;
  const int l15 = lane & 15, l4 = lane >> 4;
  const u16* qbase = q + ((size_t)bh * 1024 + qb * 64) * 64;
  const u16* kbase = k + (size_t)bh * 1024 * 64;
  const u16* vbase = v + (size_t)bh * 1024 * 64;
#pragma unroll
  for (int i = 0; i < 2; ++i) {
    int c = i * 256 + tid;
    glds16(qbase + c * 8, &Qs[c * 8]);
  }
  __syncthreads();
  bf16x8 qf[2];
#pragma unroll
  for (int ch = 0; ch < 2; ++ch)
    qf[ch] = *reinterpret_cast<const bf16x8*>(&Qs[(w * 16 + l15) * 64 + ch * 32 + l4 * 8]);

  f32x4 oacc[4];
#pragma unroll
  for (int n = 0; n < 4; ++n) oacc[n] = (f32x4){0.f, 0.f, 0.f, 0.f};
  float mrow[4], lrow[4];
#pragma unroll
  for (int r = 0; r < 4; ++r) { mrow[r] = -3.0e38f; lrow[r] = 0.f; }

  for (int kv0 = 0; kv0 < 1024; kv0 += 32) {
    __syncthreads();
    glds16(kbase + (size_t)kv0 * 64 + tid * 8, &Ks[tid * 8]);
    {
      int r = tid >> 3, c0 = (tid & 7) * 8;
      u16x8 vv = *reinterpret_cast<const u16x8*>(vbase + (size_t)(kv0 + r) * 64 + c0);
#pragma unroll
      for (int i = 0; i < 8; ++i) Vt[(c0 + i) * 32 + r] = vv[i];
    }
    __syncthreads();

    f32x4 st[2];
#pragma unroll
    for (int tile = 0; tile < 2; ++tile) {
      f32x4 s = (f32x4){0.f, 0.f, 0.f, 0.f};
#pragma unroll
      for (int ch = 0; ch < 2; ++ch) {
        bf16x8 kf = *reinterpret_cast<const bf16x8*>(
            &Ks[(tile * 16 + l15) * 64 + ch * 32 + l4 * 8]);
        s = __builtin_amdgcn_mfma_f32_16x16x32_bf16(qf[ch], kf, s, 0, 0, 0);
      }
      st[tile] = s;
    }

    float tmax[4];
#pragma unroll
    for (int r = 0; r < 4; ++r) tmax[r] = fmaxf(st[0][r], st[1][r]);
#pragma unroll
    for (int md = 1; md < 16; md <<= 1)
#pragma unroll
      for (int r = 0; r < 4; ++r) tmax[r] = fmaxf(tmax[r], __shfl_xor(tmax[r], md, 64));

    float alpha[4], pr[2][4], rsum[4];
#pragma unroll
    for (int r = 0; r < 4; ++r) {
      float mnew = fmaxf(mrow[r], tmax[r]);
      alpha[r] = __expf(mrow[r] - mnew);
      mrow[r] = mnew;
      pr[0][r] = __expf(st[0][r] - mnew);
      pr[1][r] = __expf(st[1][r] - mnew);
      rsum[r] = pr[0][r] + pr[1][r];
    }
#pragma unroll
    for (int md = 1; md < 16; md <<= 1)
#pragma unroll
      for (int r = 0; r < 4; ++r) rsum[r] += __shfl_xor(rsum[r], md, 64);
#pragma unroll
    for (int r = 0; r < 4; ++r) lrow[r] = lrow[r] * alpha[r] + rsum[r];
#pragma unroll
    for (int n = 0; n < 4; ++n)
#pragma unroll
      for (int r = 0; r < 4; ++r) oacc[n][r] *= alpha[r];

#pragma unroll
    for (int tile = 0; tile < 2; ++tile)
#pragma unroll
      for (int r = 0; r < 4; ++r)
        Ps[w][(l4 * 4 + r) * 32 + tile * 16 + l15] = f2bf(pr[tile][r]);
    __syncthreads();

    bf16x8 pf = *reinterpret_cast<const bf16x8*>(&Ps[w][l15 * 32 + l4 * 8]);
#pragma unroll
    for (int n = 0; n < 4; ++n) {
      bf16x8 vf = *reinterpret_cast<const bf16x8*>(&Vt[(n * 16 + l15) * 32 + l4 * 8]);
      oacc[n] = __builtin_amdgcn_mfma_f32_16x16x32_bf16(pf, vf, oacc[n], 0, 0, 0);
    }
  }

  float invl[4];
#pragma unroll
  for (int r = 0; r < 4; ++r) invl[r] = 1.0f / lrow[r];
#pragma unroll
  for (int n = 0; n < 4; ++n)
#pragma unroll
    for (int r = 0; r < 4; ++r) {
      int nr = qb * 64 + w * 16 + l4 * 4 + r;
      int dc = n * 16 + l15;
      o[((size_t)(b * 1024 + nr)) * 1024 + h * 64 + dc] = f2bf(oacc[n][r] * invl[r]);
    }
}

extern "C" void kernel_launch(void* const* d_in, const int* in_sizes, int n_in,
                              void* d_out, int out_size, void* d_ws, size_t ws_size,
                              hipStream_t stream) {
  (void)in_sizes; (void)n_in; (void)out_size; (void)ws_size;
  const float* x     = (const float*)d_in[0];
  const float* ln1w  = (const float*)d_in[1];
  const float* ln1b  = (const float*)d_in[2];
  const float* Wq    = (const float*)d_in[3];
  const float* bq    = (const float*)d_in[4];
  const float* Wk    = (const float*)d_in[5];
  const float* bk    = (const float*)d_in[6];
  const float* Wv    = (const float*)d_in[7];
  const float* bv    = (const float*)d_in[8];
  const float* Wo    = (const float*)d_in[9];
  const float* bo    = (const float*)d_in[10];
  const float* ln2w  = (const float*)d_in[11];
  const float* ln2b  = (const float*)d_in[12];
  const float* Wfc   = (const float*)d_in[13];
  const float* bfc   = (const float*)d_in[14];
  const float* Wproj = (const float*)d_in[15];
  const float* bproj = (const float*)d_in[16];
  float* out = (float*)d_out;

  char* p = (char*)d_ws;
  u16* hb     = (u16*)p; p += (size_t)4096 * 1024 * 2;   // LN1 out bf16
  u16* WqkvT  = (u16*)p; p += (size_t)3072 * 1024 * 2;   // [3072][1024] bf16
  u16* WoT    = (u16*)p; p += (size_t)1024 * 1024 * 2;
  u16* WfcT   = (u16*)p; p += (size_t)4096 * 1024 * 2;
  u16* WprojT = (u16*)p; p += (size_t)1024 * 4096 * 2;
  u16* qb_    = (u16*)p; p += (size_t)4096 * 1024 * 2;   // [BH][N][64]
  u16* kb_    = (u16*)p; p += (size_t)4096 * 1024 * 2;
  u16* vb_    = (u16*)p; p += (size_t)4096 * 1024 * 2;
  u16* ob_    = (u16*)p; p += (size_t)4096 * 1024 * 2;   // attn out [T][1024]
  float* x1   = (float*)p; p += (size_t)4096 * 1024 * 4; // residual 1 fp32
  u16* h2     = (u16*)p; p += (size_t)4096 * 1024 * 2;   // LN2 out bf16
  u16* ffnb   = (u16*)p; p += (size_t)4096 * 4096 * 2;   // gelu out bf16

  dim3 tb(32, 8);
  transpose_bf16<<<dim3(32, 32), tb, 0, stream>>>(Wq, WqkvT, 1024, 1024);
  transpose_bf16<<<dim3(32, 32), tb, 0, stream>>>(Wk, WqkvT + (size_t)1024 * 1024, 1024, 1024);
  transpose_bf16<<<dim3(32, 32), tb, 0, stream>>>(Wv, WqkvT + (size_t)2048 * 1024, 1024, 1024);
  transpose_bf16<<<dim3(32, 32), tb, 0, stream>>>(Wo, WoT, 1024, 1024);
  transpose_bf16<<<dim3(128, 32), tb, 0, stream>>>(Wfc, WfcT, 1024, 4096);
  transpose_bf16<<<dim3(32, 128), tb, 0, stream>>>(Wproj, WprojT, 4096, 1024);

  ln_kernel<<<4096, 256, 0, stream>>>(x, ln1w, ln1b, hb);

  gemm128<0><<<dim3(32, 24), 256, 0, stream>>>(hb, WqkvT, bq, bk, bv, nullptr,
                                               qb_, kb_, vb_, nullptr,
                                               4096, 3072, 1024, 0.125f);

  attn_kernel<<<dim3(64, 16), 256, 0, stream>>>(qb_, kb_, vb_, ob_);

  gemm128<1><<<dim3(32, 8), 256, 0, stream>>>(ob_, WoT, bo, nullptr, nullptr, x,
                                              nullptr, nullptr, nullptr, x1,
                                              4096, 1024, 1024, 1.f);

  ln_kernel<<<4096, 256, 0, stream>>>(x1, ln2w, ln2b, h2);

  gemm128<2><<<dim3(32, 32), 256, 0, stream>>>(h2, WfcT, bfc, nullptr, nullptr, nullptr,
                                               ffnb, nullptr, nullptr, nullptr,
                                               4096, 4096, 1024, 1.f);

  gemm128<1><<<dim3(32, 8), 256, 0, stream>>>(ffnb, WprojT, bproj, nullptr, nullptr, x1,
                                              nullptr, nullptr, nullptr, out,
                                              4096, 1024, 4096, 1.f);
}

// Round 2
// 391.512 us; speedup vs baseline: 1.2332x; 1.2332x over previous
//
#include <hip/hip_runtime.h>
#include <hip/hip_bf16.h>

typedef unsigned short u16;
typedef u16 u16x8 __attribute__((ext_vector_type(8)));
typedef u16 u16x4 __attribute__((ext_vector_type(4)));
typedef __bf16 bf16x8 __attribute__((ext_vector_type(8)));
typedef float f32x4 __attribute__((ext_vector_type(4)));

__device__ __forceinline__ u16 f2bf(float f) {
  union { __hip_bfloat16 h; u16 u; } cv;
  cv.h = __float2bfloat16(f);
  return cv.u;
}

__device__ __forceinline__ void glds16(const void* g, void* l) {
  __builtin_amdgcn_global_load_lds(
      (const __attribute__((address_space(1))) unsigned int*)g,
      (__attribute__((address_space(3))) unsigned int*)l, 16, 0, 0);
}

// ---------------- transpose + fp32->bf16 convert:  W[K][N] -> Wt[N][K] ----------------
__global__ __launch_bounds__(256) void transpose_bf16(const float* __restrict__ W,
                                                      u16* __restrict__ Wt,
                                                      int K, int N) {
  __shared__ float tile[32][33];
  int tx = threadIdx.x, ty = threadIdx.y;
  int n0 = blockIdx.x * 32, k0 = blockIdx.y * 32;
#pragma unroll
  for (int j = 0; j < 4; ++j)
    tile[ty + j * 8][tx] = W[(size_t)(k0 + ty + j * 8) * N + n0 + tx];
  __syncthreads();
#pragma unroll
  for (int j = 0; j < 4; ++j)
    Wt[(size_t)(n0 + ty + j * 8) * K + k0 + tx] = f2bf(tile[tx][ty + j * 8]);
}

// ---------------- LayerNorm: fp32 in [rows][1024] -> bf16 out ----------------
__global__ __launch_bounds__(256) void ln_kernel(const float* __restrict__ x,
                                                 const float* __restrict__ w,
                                                 const float* __restrict__ b,
                                                 u16* __restrict__ out) {
  int row = blockIdx.x, t = threadIdx.x;
  const float* xr = x + (size_t)row * 1024;
  float4 v = *reinterpret_cast<const float4*>(xr + t * 4);
  float s = v.x + v.y + v.z + v.w;
  float s2 = v.x * v.x + v.y * v.y + v.z * v.z + v.w * v.w;
#pragma unroll
  for (int m = 1; m < 64; m <<= 1) {
    s += __shfl_xor(s, m, 64);
    s2 += __shfl_xor(s2, m, 64);
  }
  __shared__ float red[8];
  if ((t & 63) == 0) { red[t >> 6] = s; red[(t >> 6) + 4] = s2; }
  __syncthreads();
  s = red[0] + red[1] + red[2] + red[3];
  s2 = red[4] + red[5] + red[6] + red[7];
  float mu = s * (1.f / 1024.f);
  float var = s2 * (1.f / 1024.f) - mu * mu;
  float rs = rsqrtf(var + 1e-5f);
  float4 wv = *reinterpret_cast<const float4*>(w + t * 4);
  float4 bv = *reinterpret_cast<const float4*>(b + t * 4);
  u16x4 o;
  o.x = f2bf((v.x - mu) * rs * wv.x + bv.x);
  o.y = f2bf((v.y - mu) * rs * wv.y + bv.y);
  o.z = f2bf((v.z - mu) * rs * wv.z + bv.z);
  o.w = f2bf((v.w - mu) * rs * wv.w + bv.w);
  *reinterpret_cast<u16x4*>(out + (size_t)row * 1024 + t * 4) = o;
}

// ---------------- MFMA GEMM: C[M,N] = A[M,K] @ Bt[N,K]^T (+epilogue) ----------------
// Double-buffered LDS, prefetch next K-tile while computing current (T3-minimum).
// MODE 0: QKV scatter -> q/k [BH,N,64] bf16 (q pre-scaled), V^T [BH,64,N] bf16
// MODE 1: fp32 of = acc + bias + res
// MODE 2: bf16 o0 = gelu_exact(acc + bias)
template <int MODE, int TN>
__global__ __launch_bounds__(256) void gemm_k(
    const u16* __restrict__ A, const u16* __restrict__ Bt,
    const float* __restrict__ b0, const float* __restrict__ b1,
    const float* __restrict__ b2, const float* __restrict__ res,
    u16* __restrict__ o0, u16* __restrict__ o1, u16* __restrict__ vt,
    float* __restrict__ of, int M, int N, int K, float qscale) {
  constexpr int WHALF = TN / 2;
  constexpr int NF = TN / 32;  // n-frags per wave: 4 (TN=128) or 2 (TN=64)
  __shared__ u16 As[2][128 * 32];
  __shared__ u16 Bs[2][TN * 32];
  const int tid = threadIdx.x;
  const int lane = tid & 63, w = tid >> 6;
  const int wr = w >> 1, wc = w & 1;
  const int l15 = lane & 15, l4 = lane >> 4;
  const int row0 = blockIdx.x * 128, col0 = blockIdx.y * TN;
  f32x4 acc[4][NF];
#pragma unroll
  for (int m = 0; m < 4; ++m)
#pragma unroll
    for (int n = 0; n < NF; ++n) acc[m][n] = (f32x4){0.f, 0.f, 0.f, 0.f};

  auto stage = [&](int buf, int k0) {
#pragma unroll
    for (int i = 0; i < 2; ++i) {
      int c = i * 256 + tid;
      glds16(A + (size_t)(row0 + (c >> 2)) * K + k0 + (c & 3) * 8, &As[buf][c * 8]);
    }
    if constexpr (TN == 128) {
#pragma unroll
      for (int i = 0; i < 2; ++i) {
        int c = i * 256 + tid;
        glds16(Bt + (size_t)(col0 + (c >> 2)) * K + k0 + (c & 3) * 8, &Bs[buf][c * 8]);
      }
    } else {
      int c = tid;
      glds16(Bt + (size_t)(col0 + (c >> 2)) * K + k0 + (c & 3) * 8, &Bs[buf][c * 8]);
    }
  };

  stage(0, 0);
  __syncthreads();
  const int nk = K >> 5;
  for (int t = 0; t < nk; ++t) {
    int cur = t & 1;
    if (t + 1 < nk) stage(cur ^ 1, (t + 1) << 5);
    bf16x8 af[4], bfr[NF];
#pragma unroll
    for (int m = 0; m < 4; ++m)
      af[m] = *reinterpret_cast<const bf16x8*>(&As[cur][(wr * 64 + m * 16 + l15) * 32 + l4 * 8]);
#pragma unroll
    for (int n = 0; n < NF; ++n)
      bfr[n] = *reinterpret_cast<const bf16x8*>(&Bs[cur][(wc * WHALF + n * 16 + l15) * 32 + l4 * 8]);
#pragma unroll
    for (int m = 0; m < 4; ++m)
#pragma unroll
      for (int n = 0; n < NF; ++n)
        acc[m][n] = __builtin_amdgcn_mfma_f32_16x16x32_bf16(af[m], bfr[n], acc[m][n], 0, 0, 0);
    __syncthreads();
  }

  if constexpr (MODE == 0) {
    const int which = (int)(blockIdx.y >> 3);  // 0=Q,1=K,2=V (col0 multiple of 128, 8 blocks/1024)
    const int bidx = (int)(blockIdx.x >> 3);   // batch (row0 multiple of 128, 8 blocks/1024)
#pragma unroll
    for (int m = 0; m < 4; ++m)
#pragma unroll
      for (int n = 0; n < NF; ++n) {
        int colc = (col0 & 1023) + wc * WHALF + n * 16 + l15;
        int hh = colc >> 6, d = colc & 63;
        int nb = (row0 & 1023) + wr * 64 + m * 16 + l4 * 4;
        if (which == 2) {
          u16x4 pk;
#pragma unroll
          for (int r = 0; r < 4; ++r) pk[r] = f2bf(acc[m][n][r] + b2[colc]);
          *reinterpret_cast<u16x4*>(
              vt + (((size_t)(bidx * 16 + hh) * 64 + d) * 1024 + nb)) = pk;
        } else {
          const float* bb = (which == 0) ? b0 : b1;
          u16* dst = (which == 0) ? o0 : o1;
          float sc = (which == 0) ? qscale : 1.0f;
#pragma unroll
          for (int r = 0; r < 4; ++r)
            dst[((size_t)(bidx * 16 + hh) * 1024 + nb + r) * 64 + d] =
                f2bf((acc[m][n][r] + bb[colc]) * sc);
        }
      }
  } else {
#pragma unroll
    for (int m = 0; m < 4; ++m)
#pragma unroll
      for (int n = 0; n < NF; ++n)
#pragma unroll
        for (int r = 0; r < 4; ++r) {
          int row = row0 + wr * 64 + m * 16 + l4 * 4 + r;
          int col = col0 + wc * WHALF + n * 16 + l15;
          float val = acc[m][n][r];
          if constexpr (MODE == 1) {
            of[(size_t)row * N + col] = val + b0[col] + res[(size_t)row * N + col];
          } else {
            val += b0[col];
            float g = 0.5f * val * (1.0f + erff(val * 0.70710678118f));
            o0[(size_t)row * N + col] = f2bf(g);
          }
        }
  }
}

// ---------------- fused flash attention ----------------
// q,k: [BH, N, 64] bf16 (q pre-scaled by 0.125*log2e); vt: [BH, 64, N] bf16
// out o: [B, N, 1024] bf16. KVBLK=64, double-buffered, XOR-swizzled LDS.
__global__ __launch_bounds__(256) void attn_kernel(const u16* __restrict__ q,
                                                   const u16* __restrict__ k,
                                                   const u16* __restrict__ vt,
                                                   u16* __restrict__ o) {
  const int bh = blockIdx.x, qb = blockIdx.y;
  const int b = bh >> 4, h = bh & 15;
  __shared__ u16 Ks[2][4096];
  __shared__ u16 Vt[2][4096];
  __shared__ u16 Ps[4][1024];
  const int tid = threadIdx.x, lane = tid & 63, w = tid >> 6;
  const int l15 = lane & 15, l4 = lane >> 4;
  const int sw = l15 & 7;  // row-dependent swizzle key for fragment reads
  const u16* kbase = k + (size_t)bh * 65536;
  const u16* vtbase = vt + (size_t)bh * 65536;

  // Q fragments straight from global (per-lane contiguous 16B, no LDS needed)
  const u16* qrow = q + ((size_t)bh * 1024 + qb * 64 + w * 16 + l15) * 64;
  bf16x8 qf0 = *reinterpret_cast<const bf16x8*>(qrow + l4 * 8);
  bf16x8 qf1 = *reinterpret_cast<const bf16x8*>(qrow + 32 + l4 * 8);

  auto stageKV = [&](int buf, int kv0) {
#pragma unroll
    for (int i = 0; i < 2; ++i) {
      int c = i * 256 + tid, r = c >> 3, sl = (c & 7) ^ (r & 7);
      glds16(kbase + (size_t)(kv0 + r) * 64 + sl * 8, &Ks[buf][c * 8]);
    }
#pragma unroll
    for (int i = 0; i < 2; ++i) {
      int c = i * 256 + tid, r = c >> 3, sl = (c & 7) ^ (r & 7);
      glds16(vtbase + (size_t)r * 1024 + kv0 + sl * 8, &Vt[buf][c * 8]);
    }
  };

  f32x4 oacc[4];
#pragma unroll
  for (int n = 0; n < 4; ++n) oacc[n] = (f32x4){0.f, 0.f, 0.f, 0.f};
  float mrow[4], lrow[4];
#pragma unroll
  for (int r = 0; r < 4; ++r) { mrow[r] = -3.0e38f; lrow[r] = 0.f; }

  stageKV(0, 0);
  __syncthreads();

  for (int kv0 = 0; kv0 < 1024; kv0 += 64) {
    int cur = (kv0 >> 6) & 1;
    if (kv0 + 64 < 1024) stageKV(cur ^ 1, kv0 + 64);

    // S = Q K^T (exp2 domain, q pre-scaled)
    f32x4 st[4];
#pragma unroll
    for (int t = 0; t < 4; ++t) {
      int row = t * 16 + l15;
      f32x4 s = (f32x4){0.f, 0.f, 0.f, 0.f};
      bf16x8 kf0 = *reinterpret_cast<const bf16x8*>(&Ks[cur][row * 64 + ((l4 ^ sw) << 3)]);
      s = __builtin_amdgcn_mfma_f32_16x16x32_bf16(qf0, kf0, s, 0, 0, 0);
      bf16x8 kf1 = *reinterpret_cast<const bf16x8*>(&Ks[cur][row * 64 + (((4 + l4) ^ sw) << 3)]);
      s = __builtin_amdgcn_mfma_f32_16x16x32_bf16(qf1, kf1, s, 0, 0, 0);
      st[t] = s;
    }

    // online softmax (base-2)
    float tmax[4];
#pragma unroll
    for (int r = 0; r < 4; ++r)
      tmax[r] = fmaxf(fmaxf(st[0][r], st[1][r]), fmaxf(st[2][r], st[3][r]));
#pragma unroll
    for (int md = 1; md < 16; md <<= 1)
#pragma unroll
      for (int r = 0; r < 4; ++r) tmax[r] = fmaxf(tmax[r], __shfl_xor(tmax[r], md, 64));
    float pr[4][4], alpha[4], rsum[4];
#pragma unroll
    for (int r = 0; r < 4; ++r) {
      float mnew = fmaxf(mrow[r], tmax[r]);
      alpha[r] = exp2f(mrow[r] - mnew);
      mrow[r] = mnew;
#pragma unroll
      for (int t = 0; t < 4; ++t) pr[t][r] = exp2f(st[t][r] - mnew);
      rsum[r] = (pr[0][r] + pr[1][r]) + (pr[2][r] + pr[3][r]);
    }
#pragma unroll
    for (int md = 1; md < 16; md <<= 1)
#pragma unroll
      for (int r = 0; r < 4; ++r) rsum[r] += __shfl_xor(rsum[r], md, 64);
#pragma unroll
    for (int r = 0; r < 4; ++r) lrow[r] = lrow[r] * alpha[r] + rsum[r];
#pragma unroll
    for (int n = 0; n < 4; ++n)
#pragma unroll
      for (int r = 0; r < 4; ++r) oacc[n][r] *= alpha[r];

    // P -> per-wave swizzled LDS (write C-layout, read A-fragment layout)
#pragma unroll
    for (int t = 0; t < 4; ++t)
#pragma unroll
      for (int r = 0; r < 4; ++r) {
        int qq = l4 * 4 + r, kv = t * 16 + l15;
        Ps[w][qq * 64 + ((((kv >> 3) ^ (qq & 7)) << 3) | (kv & 7))] = f2bf(pr[t][r]);
      }

    // O += P @ V  (V^T rows are d -> same fragment pattern as K)
#pragma unroll
    for (int c2 = 0; c2 < 2; ++c2) {
      bf16x8 pf = *reinterpret_cast<const bf16x8*>(
          &Ps[w][l15 * 64 + ((((c2 << 2) + l4) ^ sw) << 3)]);
#pragma unroll
      for (int n = 0; n < 4; ++n) {
        bf16x8 vf = *reinterpret_cast<const bf16x8*>(
            &Vt[cur][(n * 16 + l15) * 64 + ((((c2 << 2) + l4) ^ sw) << 3)]);
        oacc[n] = __builtin_amdgcn_mfma_f32_16x16x32_bf16(pf, vf, oacc[n], 0, 0, 0);
      }
    }
    __syncthreads();
  }

  float invl[4];
#pragma unroll
  for (int r = 0; r < 4; ++r) invl[r] = 1.0f / lrow[r];
#pragma unroll
  for (int n = 0; n < 4; ++n)
#pragma unroll
    for (int r = 0; r < 4; ++r) {
      int nr = qb * 64 + w * 16 + l4 * 4 + r;
      int dc = n * 16 + l15;
      o[((size_t)(b * 1024 + nr)) * 1024 + h * 64 + dc] = f2bf(oacc[n][r] * invl[r]);
    }
}

extern "C" void kernel_launch(void* const* d_in, const int* in_sizes, int n_in,
                              void* d_out, int out_size, void* d_ws, size_t ws_size,
                              hipStream_t stream) {
  (void)in_sizes; (void)n_in; (void)out_size; (void)ws_size;
  const float* x     = (const float*)d_in[0];
  const float* ln1w  = (const float*)d_in[1];
  const float* ln1b  = (const float*)d_in[2];
  const float* Wq    = (const float*)d_in[3];
  const float* bq    = (const float*)d_in[4];
  const float* Wk    = (const float*)d_in[5];
  const float* bk    = (const float*)d_in[6];
  const float* Wv    = (const float*)d_in[7];
  const float* bv    = (const float*)d_in[8];
  const float* Wo    = (const float*)d_in[9];
  const float* bo    = (const float*)d_in[10];
  const float* ln2w  = (const float*)d_in[11];
  const float* ln2b  = (const float*)d_in[12];
  const float* Wfc   = (const float*)d_in[13];
  const float* bfc   = (const float*)d_in[14];
  const float* Wproj = (const float*)d_in[15];
  const float* bproj = (const float*)d_in[16];
  float* out = (float*)d_out;

  char* p = (char*)d_ws;
  u16* hb     = (u16*)p; p += (size_t)4096 * 1024 * 2;   // LN1 out bf16
  u16* WqkvT  = (u16*)p; p += (size_t)3072 * 1024 * 2;   // [3072][1024] bf16
  u16* WoT    = (u16*)p; p += (size_t)1024 * 1024 * 2;
  u16* WfcT   = (u16*)p; p += (size_t)4096 * 1024 * 2;
  u16* WprojT = (u16*)p; p += (size_t)1024 * 4096 * 2;
  u16* qb_    = (u16*)p; p += (size_t)4096 * 1024 * 2;   // [BH][N][64]
  u16* kb_    = (u16*)p; p += (size_t)4096 * 1024 * 2;   // [BH][N][64]
  u16* vt_    = (u16*)p; p += (size_t)4096 * 1024 * 2;   // [BH][64][N]  (V transposed)
  u16* ob_    = (u16*)p; p += (size_t)4096 * 1024 * 2;   // attn out [T][1024]
  float* x1   = (float*)p; p += (size_t)4096 * 1024 * 4; // residual 1 fp32
  u16* h2     = (u16*)p; p += (size_t)4096 * 1024 * 2;   // LN2 out bf16
  u16* ffnb   = (u16*)p; p += (size_t)4096 * 4096 * 2;   // gelu out bf16

  const float qscale = 0.125f * 1.44269504089f;  // 1/sqrt(64) * log2(e)

  dim3 tb(32, 8);
  transpose_bf16<<<dim3(32, 32), tb, 0, stream>>>(Wq, WqkvT, 1024, 1024);
  transpose_bf16<<<dim3(32, 32), tb, 0, stream>>>(Wk, WqkvT + (size_t)1024 * 1024, 1024, 1024);
  transpose_bf16<<<dim3(32, 32), tb, 0, stream>>>(Wv, WqkvT + (size_t)2048 * 1024, 1024, 1024);
  transpose_bf16<<<dim3(32, 32), tb, 0, stream>>>(Wo, WoT, 1024, 1024);
  transpose_bf16<<<dim3(128, 32), tb, 0, stream>>>(Wfc, WfcT, 1024, 4096);
  transpose_bf16<<<dim3(32, 128), tb, 0, stream>>>(Wproj, WprojT, 4096, 1024);

  ln_kernel<<<4096, 256, 0, stream>>>(x, ln1w, ln1b, hb);

  gemm_k<0, 128><<<dim3(32, 24), 256, 0, stream>>>(hb, WqkvT, bq, bk, bv, nullptr,
                                                   qb_, kb_, vt_, nullptr,
                                                   4096, 3072, 1024, qscale);

  attn_kernel<<<dim3(64, 16), 256, 0, stream>>>(qb_, kb_, vt_, ob_);

  gemm_k<1, 64><<<dim3(32, 16), 256, 0, stream>>>(ob_, WoT, bo, nullptr, nullptr, x,
                                                  nullptr, nullptr, nullptr, x1,
                                                  4096, 1024, 1024, 1.f);

  ln_kernel<<<4096, 256, 0, stream>>>(x1, ln2w, ln2b, h2);

  gemm_k<2, 128><<<dim3(32, 32), 256, 0, stream>>>(h2, WfcT, bfc, nullptr, nullptr, nullptr,
                                                   ffnb, nullptr, nullptr, nullptr,
                                                   4096, 4096, 1024, 1.f);

  gemm_k<1, 64><<<dim3(32, 16), 256, 0, stream>>>(ffnb, WprojT, bproj, nullptr, nullptr, x1,
                                                  nullptr, nullptr, nullptr, out,
                                                  4096, 1024, 4096, 1.f);
}

// Round 3
// 376.233 us; speedup vs baseline: 1.2832x; 1.0406x over previous
//
#include <hip/hip_runtime.h>
#include <hip/hip_bf16.h>

typedef unsigned short u16;
typedef u16 u16x8 __attribute__((ext_vector_type(8)));
typedef u16 u16x4 __attribute__((ext_vector_type(4)));
typedef __bf16 bf16x8 __attribute__((ext_vector_type(8)));
typedef float f32x4 __attribute__((ext_vector_type(4)));

__device__ __forceinline__ u16 f2bf(float f) {
  union { __hip_bfloat16 h; u16 u; } cv;
  cv.h = __float2bfloat16(f);
  return cv.u;
}
__device__ __forceinline__ float bf2f(u16 u) {
  union { unsigned u; float f; } c;
  c.u = ((unsigned)u) << 16;
  return c.f;
}

__device__ __forceinline__ void glds16(const void* g, void* l) {
  __builtin_amdgcn_global_load_lds(
      (const __attribute__((address_space(1))) unsigned int*)g,
      (__attribute__((address_space(3))) unsigned int*)l, 16, 0, 0);
}

// ---------------- transpose + fp32->bf16 convert:  W[K][N] -> Wt[N][K] ----------------
__global__ __launch_bounds__(256) void transpose_bf16(const float* __restrict__ W,
                                                      u16* __restrict__ Wt,
                                                      int K, int N) {
  __shared__ float tile[32][33];
  int tx = threadIdx.x, ty = threadIdx.y;
  int n0 = blockIdx.x * 32, k0 = blockIdx.y * 32;
#pragma unroll
  for (int j = 0; j < 4; ++j)
    tile[ty + j * 8][tx] = W[(size_t)(k0 + ty + j * 8) * N + n0 + tx];
  __syncthreads();
#pragma unroll
  for (int j = 0; j < 4; ++j)
    Wt[(size_t)(n0 + ty + j * 8) * K + k0 + tx] = f2bf(tile[tx][ty + j * 8]);
}

// ---------------- LayerNorm: fp32 in [rows][1024] -> bf16 out ----------------
__global__ __launch_bounds__(256) void ln_kernel(const float* __restrict__ x,
                                                 const float* __restrict__ w,
                                                 const float* __restrict__ b,
                                                 u16* __restrict__ out) {
  int row = blockIdx.x, t = threadIdx.x;
  const float* xr = x + (size_t)row * 1024;
  float4 v = *reinterpret_cast<const float4*>(xr + t * 4);
  float s = v.x + v.y + v.z + v.w;
  float s2 = v.x * v.x + v.y * v.y + v.z * v.z + v.w * v.w;
#pragma unroll
  for (int m = 1; m < 64; m <<= 1) {
    s += __shfl_xor(s, m, 64);
    s2 += __shfl_xor(s2, m, 64);
  }
  __shared__ float red[8];
  if ((t & 63) == 0) { red[t >> 6] = s; red[(t >> 6) + 4] = s2; }
  __syncthreads();
  s = red[0] + red[1] + red[2] + red[3];
  s2 = red[4] + red[5] + red[6] + red[7];
  float mu = s * (1.f / 1024.f);
  float var = s2 * (1.f / 1024.f) - mu * mu;
  float rs = rsqrtf(var + 1e-5f);
  float4 wv = *reinterpret_cast<const float4*>(w + t * 4);
  float4 bv = *reinterpret_cast<const float4*>(b + t * 4);
  u16x4 o;
  o.x = f2bf((v.x - mu) * rs * wv.x + bv.x);
  o.y = f2bf((v.y - mu) * rs * wv.y + bv.y);
  o.z = f2bf((v.z - mu) * rs * wv.z + bv.z);
  o.w = f2bf((v.w - mu) * rs * wv.w + bv.w);
  *reinterpret_cast<u16x4*>(out + (size_t)row * 1024 + t * 4) = o;
}

// ================= 256x256 8-phase MFMA GEMM (T1+T2+T3+T4+T5) =================
// C[M,N] = A[M,Kfull(range kbase..kbase+KL)] @ Bt[N,:]^T
// 8 waves (2Mx4N), BK=64 split in two K-halves of 32; LDS 128KB double-buffered.
// Stage schedule per K-tile t (all into the NON-live buffer):
//   p0: A.ks0(t+1)   p1: A.ks1(t+1)+vmcnt(4)   p2: B.ks0(t+1)   p3: B.ks1(t+1)+vmcnt(2)
// Swizzle: LDS[r][ch] holds global chunk ch^((r>>1)&3)  (16B chunks, 4/row) -> 2-way banks.
// MODE 0: QKV scatter (q pre-scaled). MODE 2: bf16 gelu(acc+bias). MODE 3: bf16 raw partials.
template <int MODE>
__global__ __launch_bounds__(512, 2) void gemm256(
    const u16* __restrict__ A, const u16* __restrict__ Bt,
    const float* __restrict__ b0, const float* __restrict__ b1,
    const float* __restrict__ b2,
    u16* __restrict__ o0, u16* __restrict__ o1, u16* __restrict__ o2,
    int Kfull, int KL, int MT, int NT, float qscale) {
  __shared__ u16 lds[2][2][2][256 * 32];  // [buf][op A0/B1][khalf][256 rows x 32 cols]
  const int tid = threadIdx.x;
  const int lane = tid & 63, w = tid >> 6;
  const int wm = w >> 2, wn = w & 3;
  const int l15 = lane & 15, l4 = lane >> 4;
  const int skey = (l15 >> 1) & 3;

  // XCD-bijective swizzle (all our grids are %8==0)
  const int nwg = gridDim.x;
  int wg = (int)blockIdx.x;
  wg = (wg & 7) * (nwg >> 3) + (wg >> 3);
  const int mt = wg % MT;
  int rest = wg / MT;
  const int nt = rest % NT;
  const int zt = rest / NT;

  const int row0 = mt * 256, col0 = nt * 256;
  const int kbase = zt * KL;
  const int nkt = KL >> 6;

  auto stage = [&](int buf, int op, int ks, int kt) {
    const u16* src = op ? Bt : A;
    const int base = op ? col0 : row0;
    const int kb = kbase + (kt << 6) + (ks << 5);
    u16* dst = &lds[buf][op][ks][0];
#pragma unroll
    for (int i = 0; i < 2; ++i) {
      int c = i * 512 + tid;
      int r = c >> 2, ch = c & 3;
      int sch = ch ^ ((r >> 1) & 3);
      glds16(src + (size_t)(base + r) * Kfull + kb + sch * 8, dst + c * 8);
    }
  };
  auto rdA = [&](int buf, int ks, int m) -> bf16x8 {
    int row = wm * 128 + m * 16 + l15;
    return *reinterpret_cast<const bf16x8*>(&lds[buf][0][ks][row * 32 + ((l4 ^ skey) << 3)]);
  };
  auto rdB = [&](int buf, int ks, int n) -> bf16x8 {
    int row = wn * 64 + n * 16 + l15;
    return *reinterpret_cast<const bf16x8*>(&lds[buf][1][ks][row * 32 + ((l4 ^ skey) << 3)]);
  };

  f32x4 acc[8][4];
#pragma unroll
  for (int m = 0; m < 8; ++m)
#pragma unroll
    for (int n = 0; n < 4; ++n) acc[m][n] = (f32x4){0.f, 0.f, 0.f, 0.f};

  // prologue: stage K0 fully; force A.ks0,A.ks1,B.ks0 (keep B.ks1's 2 loads in flight)
  stage(0, 0, 0, 0);
  stage(0, 0, 1, 0);
  stage(0, 1, 0, 0);
  stage(0, 1, 1, 0);
  asm volatile("s_waitcnt vmcnt(2)" ::: "memory");
  __builtin_amdgcn_s_barrier();

  bf16x8 af[8];
  for (int t = 0; t < nkt; ++t) {
    const int cur = t & 1, nxt = cur ^ 1;
    const bool pf = (t + 1 < nkt);
    // ---- p0: ks0, n-half 0 ----
    {
#pragma unroll
      for (int m = 0; m < 8; ++m) af[m] = rdA(cur, 0, m);
      bf16x8 bq0 = rdB(cur, 0, 0), bq1 = rdB(cur, 0, 1);
      if (pf) stage(nxt, 0, 0, t + 1);
      __builtin_amdgcn_s_barrier();
      __builtin_amdgcn_s_setprio(1);
#pragma unroll
      for (int m = 0; m < 8; ++m) {
        acc[m][0] = __builtin_amdgcn_mfma_f32_16x16x32_bf16(af[m], bq0, acc[m][0], 0, 0, 0);
        acc[m][1] = __builtin_amdgcn_mfma_f32_16x16x32_bf16(af[m], bq1, acc[m][1], 0, 0, 0);
      }
      __builtin_amdgcn_s_setprio(0);
      __builtin_amdgcn_s_barrier();
    }
    // ---- p1: ks0, n-half 1 ----
    {
      bf16x8 bq2 = rdB(cur, 0, 2), bq3 = rdB(cur, 0, 3);
      if (pf) {
        stage(nxt, 0, 1, t + 1);
        asm volatile("s_waitcnt vmcnt(4)" ::: "memory");
      } else {
        asm volatile("s_waitcnt vmcnt(0)" ::: "memory");
      }
      __builtin_amdgcn_s_barrier();
      __builtin_amdgcn_s_setprio(1);
#pragma unroll
      for (int m = 0; m < 8; ++m) {
        acc[m][2] = __builtin_amdgcn_mfma_f32_16x16x32_bf16(af[m], bq2, acc[m][2], 0, 0, 0);
        acc[m][3] = __builtin_amdgcn_mfma_f32_16x16x32_bf16(af[m], bq3, acc[m][3], 0, 0, 0);
      }
      __builtin_amdgcn_s_setprio(0);
      __builtin_amdgcn_s_barrier();
    }
    // ---- p2: ks1, n-half 0 ----
    {
#pragma unroll
      for (int m = 0; m < 8; ++m) af[m] = rdA(cur, 1, m);
      bf16x8 bq0 = rdB(cur, 1, 0), bq1 = rdB(cur, 1, 1);
      if (pf) stage(nxt, 1, 0, t + 1);
      __builtin_amdgcn_s_barrier();
      __builtin_amdgcn_s_setprio(1);
#pragma unroll
      for (int m = 0; m < 8; ++m) {
        acc[m][0] = __builtin_amdgcn_mfma_f32_16x16x32_bf16(af[m], bq0, acc[m][0], 0, 0, 0);
        acc[m][1] = __builtin_amdgcn_mfma_f32_16x16x32_bf16(af[m], bq1, acc[m][1], 0, 0, 0);
      }
      __builtin_amdgcn_s_setprio(0);
      __builtin_amdgcn_s_barrier();
    }
    // ---- p3: ks1, n-half 1 ----
    {
      bf16x8 bq2 = rdB(cur, 1, 2), bq3 = rdB(cur, 1, 3);
      if (pf) stage(nxt, 1, 1, t + 1);
      asm volatile("s_waitcnt vmcnt(2)" ::: "memory");
      __builtin_amdgcn_s_barrier();
      __builtin_amdgcn_s_setprio(1);
#pragma unroll
      for (int m = 0; m < 8; ++m) {
        acc[m][2] = __builtin_amdgcn_mfma_f32_16x16x32_bf16(af[m], bq2, acc[m][2], 0, 0, 0);
        acc[m][3] = __builtin_amdgcn_mfma_f32_16x16x32_bf16(af[m], bq3, acc[m][3], 0, 0, 0);
      }
      __builtin_amdgcn_s_setprio(0);
      __builtin_amdgcn_s_barrier();
    }
  }

  // ---------------- epilogue ----------------
  if constexpr (MODE == 0) {
    const int which = nt >> 2;   // 0=Q,1=K,2=V
    const int bidx = mt >> 2;    // batch
#pragma unroll
    for (int m = 0; m < 8; ++m)
#pragma unroll
      for (int n = 0; n < 4; ++n) {
        int colc = (col0 & 1023) + wn * 64 + n * 16 + l15;
        int hh = colc >> 6, d = colc & 63;
        int nb = (row0 & 1023) + wm * 128 + m * 16 + l4 * 4;
        if (which == 2) {
          u16x4 pk;
#pragma unroll
          for (int r = 0; r < 4; ++r) pk[r] = f2bf(acc[m][n][r] + b2[colc]);
          *reinterpret_cast<u16x4*>(o2 + (((size_t)(bidx * 16 + hh) * 64 + d) * 1024 + nb)) = pk;
        } else {
          const float* bb = (which == 0) ? b0 : b1;
          u16* dst = (which == 0) ? o0 : o1;
          float sc = (which == 0) ? qscale : 1.0f;
#pragma unroll
          for (int r = 0; r < 4; ++r)
            dst[((size_t)(bidx * 16 + hh) * 1024 + nb + r) * 64 + d] =
                f2bf((acc[m][n][r] + bb[colc]) * sc);
        }
      }
  } else if constexpr (MODE == 2) {
    const int N = NT * 256;
#pragma unroll
    for (int m = 0; m < 8; ++m)
#pragma unroll
      for (int n = 0; n < 4; ++n)
#pragma unroll
        for (int r = 0; r < 4; ++r) {
          int row = row0 + wm * 128 + m * 16 + l4 * 4 + r;
          int col = col0 + wn * 64 + n * 16 + l15;
          float val = acc[m][n][r] + b0[col];
          float g = 0.5f * val * (1.0f + erff(val * 0.70710678118f));
          o0[(size_t)row * N + col] = f2bf(g);
        }
  } else {  // MODE 3: raw bf16 partials [zt][M][N]
    const int M = MT * 256, N = NT * 256;
    u16* base = o0 + (size_t)zt * M * N;
#pragma unroll
    for (int m = 0; m < 8; ++m)
#pragma unroll
      for (int n = 0; n < 4; ++n)
#pragma unroll
        for (int r = 0; r < 4; ++r) {
          int row = row0 + wm * 128 + m * 16 + l4 * 4 + r;
          int col = col0 + wn * 64 + n * 16 + l15;
          base[(size_t)row * N + col] = f2bf(acc[m][n][r]);
        }
  }
}

// ---------------- split-K reduce for Proj: out = sum(parts) + bias + res ----------------
__global__ __launch_bounds__(256) void proj_reduce(const u16* __restrict__ parts,
                                                   const float* __restrict__ bias,
                                                   const float* __restrict__ res,
                                                   float* __restrict__ out) {
  size_t i = ((size_t)blockIdx.x * 256 + threadIdx.x) * 8;
  int col = (int)(i & 1023);
  float s[8];
  float4 r0 = *reinterpret_cast<const float4*>(res + i);
  float4 r1 = *reinterpret_cast<const float4*>(res + i + 4);
  s[0] = r0.x; s[1] = r0.y; s[2] = r0.z; s[3] = r0.w;
  s[4] = r1.x; s[5] = r1.y; s[6] = r1.z; s[7] = r1.w;
#pragma unroll
  for (int j = 0; j < 8; ++j) s[j] += bias[col + j];
#pragma unroll
  for (int sp = 0; sp < 4; ++sp) {
    u16x8 pv = *reinterpret_cast<const u16x8*>(parts + (size_t)sp * 4096 * 1024 + i);
#pragma unroll
    for (int j = 0; j < 8; ++j) s[j] += bf2f(pv[j]);
  }
  float4 o0 = {s[0], s[1], s[2], s[3]};
  float4 o1 = {s[4], s[5], s[6], s[7]};
  *reinterpret_cast<float4*>(out + i) = o0;
  *reinterpret_cast<float4*>(out + i + 4) = o1;
}

// ---------------- legacy 128-tile GEMM (kept for Wo): MODE 1 fp32 out = acc+bias+res ----
template <int MODE, int TN>
__global__ __launch_bounds__(256) void gemm_k(
    const u16* __restrict__ A, const u16* __restrict__ Bt,
    const float* __restrict__ b0, const float* __restrict__ res,
    float* __restrict__ of, int M, int N, int K) {
  constexpr int WHALF = TN / 2;
  constexpr int NF = TN / 32;
  __shared__ u16 As[2][128 * 32];
  __shared__ u16 Bs[2][TN * 32];
  const int tid = threadIdx.x;
  const int lane = tid & 63, w = tid >> 6;
  const int wr = w >> 1, wc = w & 1;
  const int l15 = lane & 15, l4 = lane >> 4;
  const int row0 = blockIdx.x * 128, col0 = blockIdx.y * TN;
  f32x4 acc[4][NF];
#pragma unroll
  for (int m = 0; m < 4; ++m)
#pragma unroll
    for (int n = 0; n < NF; ++n) acc[m][n] = (f32x4){0.f, 0.f, 0.f, 0.f};

  auto stage = [&](int buf, int k0) {
#pragma unroll
    for (int i = 0; i < 2; ++i) {
      int c = i * 256 + tid;
      glds16(A + (size_t)(row0 + (c >> 2)) * K + k0 + (c & 3) * 8, &As[buf][c * 8]);
    }
    if constexpr (TN == 128) {
#pragma unroll
      for (int i = 0; i < 2; ++i) {
        int c = i * 256 + tid;
        glds16(Bt + (size_t)(col0 + (c >> 2)) * K + k0 + (c & 3) * 8, &Bs[buf][c * 8]);
      }
    } else {
      int c = tid;
      glds16(Bt + (size_t)(col0 + (c >> 2)) * K + k0 + (c & 3) * 8, &Bs[buf][c * 8]);
    }
  };

  stage(0, 0);
  __syncthreads();
  const int nk = K >> 5;
  for (int t = 0; t < nk; ++t) {
    int cur = t & 1;
    if (t + 1 < nk) stage(cur ^ 1, (t + 1) << 5);
    bf16x8 af[4], bfr[NF];
#pragma unroll
    for (int m = 0; m < 4; ++m)
      af[m] = *reinterpret_cast<const bf16x8*>(&As[cur][(wr * 64 + m * 16 + l15) * 32 + l4 * 8]);
#pragma unroll
    for (int n = 0; n < NF; ++n)
      bfr[n] = *reinterpret_cast<const bf16x8*>(&Bs[cur][(wc * WHALF + n * 16 + l15) * 32 + l4 * 8]);
#pragma unroll
    for (int m = 0; m < 4; ++m)
#pragma unroll
      for (int n = 0; n < NF; ++n)
        acc[m][n] = __builtin_amdgcn_mfma_f32_16x16x32_bf16(af[m], bfr[n], acc[m][n], 0, 0, 0);
    __syncthreads();
  }

#pragma unroll
  for (int m = 0; m < 4; ++m)
#pragma unroll
    for (int n = 0; n < NF; ++n)
#pragma unroll
      for (int r = 0; r < 4; ++r) {
        int row = row0 + wr * 64 + m * 16 + l4 * 4 + r;
        int col = col0 + wc * WHALF + n * 16 + l15;
        of[(size_t)row * N + col] = acc[m][n][r] + b0[col] + res[(size_t)row * N + col];
      }
}

// ---------------- fused flash attention (unchanged from round 2) ----------------
__global__ __launch_bounds__(256) void attn_kernel(const u16* __restrict__ q,
                                                   const u16* __restrict__ k,
                                                   const u16* __restrict__ vt,
                                                   u16* __restrict__ o) {
  const int bh = blockIdx.x, qb = blockIdx.y;
  const int b = bh >> 4, h = bh & 15;
  __shared__ u16 Ks[2][4096];
  __shared__ u16 Vt[2][4096];
  __shared__ u16 Ps[4][1024];
  const int tid = threadIdx.x, lane = tid & 63, w = tid >> 6;
  const int l15 = lane & 15, l4 = lane >> 4;
  const int sw = l15 & 7;
  const u16* kbase = k + (size_t)bh * 65536;
  const u16* vtbase = vt + (size_t)bh * 65536;

  const u16* qrow = q + ((size_t)bh * 1024 + qb * 64 + w * 16 + l15) * 64;
  bf16x8 qf0 = *reinterpret_cast<const bf16x8*>(qrow + l4 * 8);
  bf16x8 qf1 = *reinterpret_cast<const bf16x8*>(qrow + 32 + l4 * 8);

  auto stageKV = [&](int buf, int kv0) {
#pragma unroll
    for (int i = 0; i < 2; ++i) {
      int c = i * 256 + tid, r = c >> 3, sl = (c & 7) ^ (r & 7);
      glds16(kbase + (size_t)(kv0 + r) * 64 + sl * 8, &Ks[buf][c * 8]);
    }
#pragma unroll
    for (int i = 0; i < 2; ++i) {
      int c = i * 256 + tid, r = c >> 3, sl = (c & 7) ^ (r & 7);
      glds16(vtbase + (size_t)r * 1024 + kv0 + sl * 8, &Vt[buf][c * 8]);
    }
  };

  f32x4 oacc[4];
#pragma unroll
  for (int n = 0; n < 4; ++n) oacc[n] = (f32x4){0.f, 0.f, 0.f, 0.f};
  float mrow[4], lrow[4];
#pragma unroll
  for (int r = 0; r < 4; ++r) { mrow[r] = -3.0e38f; lrow[r] = 0.f; }

  stageKV(0, 0);
  __syncthreads();

  for (int kv0 = 0; kv0 < 1024; kv0 += 64) {
    int cur = (kv0 >> 6) & 1;
    if (kv0 + 64 < 1024) stageKV(cur ^ 1, kv0 + 64);

    f32x4 st[4];
#pragma unroll
    for (int t = 0; t < 4; ++t) {
      int row = t * 16 + l15;
      f32x4 s = (f32x4){0.f, 0.f, 0.f, 0.f};
      bf16x8 kf0 = *reinterpret_cast<const bf16x8*>(&Ks[cur][row * 64 + ((l4 ^ sw) << 3)]);
      s = __builtin_amdgcn_mfma_f32_16x16x32_bf16(qf0, kf0, s, 0, 0, 0);
      bf16x8 kf1 = *reinterpret_cast<const bf16x8*>(&Ks[cur][row * 64 + (((4 + l4) ^ sw) << 3)]);
      s = __builtin_amdgcn_mfma_f32_16x16x32_bf16(qf1, kf1, s, 0, 0, 0);
      st[t] = s;
    }

    float tmax[4];
#pragma unroll
    for (int r = 0; r < 4; ++r)
      tmax[r] = fmaxf(fmaxf(st[0][r], st[1][r]), fmaxf(st[2][r], st[3][r]));
#pragma unroll
    for (int md = 1; md < 16; md <<= 1)
#pragma unroll
      for (int r = 0; r < 4; ++r) tmax[r] = fmaxf(tmax[r], __shfl_xor(tmax[r], md, 64));
    float pr[4][4], alpha[4], rsum[4];
#pragma unroll
    for (int r = 0; r < 4; ++r) {
      float mnew = fmaxf(mrow[r], tmax[r]);
      alpha[r] = exp2f(mrow[r] - mnew);
      mrow[r] = mnew;
#pragma unroll
      for (int t = 0; t < 4; ++t) pr[t][r] = exp2f(st[t][r] - mnew);
      rsum[r] = (pr[0][r] + pr[1][r]) + (pr[2][r] + pr[3][r]);
    }
#pragma unroll
    for (int md = 1; md < 16; md <<= 1)
#pragma unroll
      for (int r = 0; r < 4; ++r) rsum[r] += __shfl_xor(rsum[r], md, 64);
#pragma unroll
    for (int r = 0; r < 4; ++r) lrow[r] = lrow[r] * alpha[r] + rsum[r];
#pragma unroll
    for (int n = 0; n < 4; ++n)
#pragma unroll
      for (int r = 0; r < 4; ++r) oacc[n][r] *= alpha[r];

#pragma unroll
    for (int t = 0; t < 4; ++t)
#pragma unroll
      for (int r = 0; r < 4; ++r) {
        int qq = l4 * 4 + r, kv = t * 16 + l15;
        Ps[w][qq * 64 + ((((kv >> 3) ^ (qq & 7)) << 3) | (kv & 7))] = f2bf(pr[t][r]);
      }

#pragma unroll
    for (int c2 = 0; c2 < 2; ++c2) {
      bf16x8 pf = *reinterpret_cast<const bf16x8*>(
          &Ps[w][l15 * 64 + ((((c2 << 2) + l4) ^ sw) << 3)]);
#pragma unroll
      for (int n = 0; n < 4; ++n) {
        bf16x8 vf = *reinterpret_cast<const bf16x8*>(
            &Vt[cur][(n * 16 + l15) * 64 + ((((c2 << 2) + l4) ^ sw) << 3)]);
        oacc[n] = __builtin_amdgcn_mfma_f32_16x16x32_bf16(pf, vf, oacc[n], 0, 0, 0);
      }
    }
    __syncthreads();
  }

  float invl[4];
#pragma unroll
  for (int r = 0; r < 4; ++r) invl[r] = 1.0f / lrow[r];
#pragma unroll
  for (int n = 0; n < 4; ++n)
#pragma unroll
    for (int r = 0; r < 4; ++r) {
      int nr = qb * 64 + w * 16 + l4 * 4 + r;
      int dc = n * 16 + l15;
      o[((size_t)(b * 1024 + nr)) * 1024 + h * 64 + dc] = f2bf(oacc[n][r] * invl[r]);
    }
}

extern "C" void kernel_launch(void* const* d_in, const int* in_sizes, int n_in,
                              void* d_out, int out_size, void* d_ws, size_t ws_size,
                              hipStream_t stream) {
  (void)in_sizes; (void)n_in; (void)out_size; (void)ws_size;
  const float* x     = (const float*)d_in[0];
  const float* ln1w  = (const float*)d_in[1];
  const float* ln1b  = (const float*)d_in[2];
  const float* Wq    = (const float*)d_in[3];
  const float* bq    = (const float*)d_in[4];
  const float* Wk    = (const float*)d_in[5];
  const float* bk    = (const float*)d_in[6];
  const float* Wv    = (const float*)d_in[7];
  const float* bv    = (const float*)d_in[8];
  const float* Wo    = (const float*)d_in[9];
  const float* bo    = (const float*)d_in[10];
  const float* ln2w  = (const float*)d_in[11];
  const float* ln2b  = (const float*)d_in[12];
  const float* Wfc   = (const float*)d_in[13];
  const float* bfc   = (const float*)d_in[14];
  const float* Wproj = (const float*)d_in[15];
  const float* bproj = (const float*)d_in[16];
  float* out = (float*)d_out;

  char* p = (char*)d_ws;
  u16* hb     = (u16*)p; p += (size_t)4096 * 1024 * 2;   // LN1 out bf16
  u16* WqkvT  = (u16*)p; p += (size_t)3072 * 1024 * 2;   // [3072][1024] bf16
  u16* WoT    = (u16*)p; p += (size_t)1024 * 1024 * 2;
  u16* WfcT   = (u16*)p; p += (size_t)4096 * 1024 * 2;
  u16* WprojT = (u16*)p; p += (size_t)1024 * 4096 * 2;
  u16* qb_    = (u16*)p; p += (size_t)4096 * 1024 * 2;   // [BH][N][64]; later: Proj partials (32MB, qb..ob)
  u16* kb_    = (u16*)p; p += (size_t)4096 * 1024 * 2;
  u16* vt_    = (u16*)p; p += (size_t)4096 * 1024 * 2;   // [BH][64][N]
  u16* ob_    = (u16*)p; p += (size_t)4096 * 1024 * 2;   // attn out [T][1024]
  float* x1   = (float*)p; p += (size_t)4096 * 1024 * 4; // residual 1 fp32
  u16* h2     = (u16*)p; p += (size_t)4096 * 1024 * 2;   // LN2 out bf16
  u16* ffnb   = (u16*)p; p += (size_t)4096 * 4096 * 2;   // gelu out bf16

  const float qscale = 0.125f * 1.44269504089f;  // 1/sqrt(64) * log2(e)

  dim3 tb(32, 8);
  transpose_bf16<<<dim3(32, 32), tb, 0, stream>>>(Wq, WqkvT, 1024, 1024);
  transpose_bf16<<<dim3(32, 32), tb, 0, stream>>>(Wk, WqkvT + (size_t)1024 * 1024, 1024, 1024);
  transpose_bf16<<<dim3(32, 32), tb, 0, stream>>>(Wv, WqkvT + (size_t)2048 * 1024, 1024, 1024);
  transpose_bf16<<<dim3(32, 32), tb, 0, stream>>>(Wo, WoT, 1024, 1024);
  transpose_bf16<<<dim3(128, 32), tb, 0, stream>>>(Wfc, WfcT, 1024, 4096);
  transpose_bf16<<<dim3(32, 128), tb, 0, stream>>>(Wproj, WprojT, 4096, 1024);

  ln_kernel<<<4096, 256, 0, stream>>>(x, ln1w, ln1b, hb);

  // QKV: M=4096, N=3072, K=1024 -> 16x12 = 192 blocks
  gemm256<0><<<192, 512, 0, stream>>>(hb, WqkvT, bq, bk, bv,
                                      qb_, kb_, vt_, 1024, 1024, 16, 12, qscale);

  attn_kernel<<<dim3(64, 16), 256, 0, stream>>>(qb_, kb_, vt_, ob_);

  // Wo: legacy 128x64-tile kernel (N=1024 -> 512 blocks)
  gemm_k<1, 64><<<dim3(32, 16), 256, 0, stream>>>(ob_, WoT, bo, x, x1, 4096, 1024, 1024);

  ln_kernel<<<4096, 256, 0, stream>>>(x1, ln2w, ln2b, h2);

  // FC: M=4096, N=4096, K=1024 -> 16x16 = 256 blocks
  gemm256<2><<<256, 512, 0, stream>>>(h2, WfcT, bfc, nullptr, nullptr,
                                      ffnb, nullptr, nullptr, 1024, 1024, 16, 16, 1.f);

  // Proj: M=4096, N=1024, K=4096, split-K=4 -> 16x4x4 = 256 blocks, bf16 partials in qb_ region
  gemm256<3><<<256, 512, 0, stream>>>(ffnb, WprojT, nullptr, nullptr, nullptr,
                                      qb_, nullptr, nullptr, 4096, 1024, 16, 4, 1.f);
  proj_reduce<<<2048, 256, 0, stream>>>(qb_, bproj, x1, out);
}

// Round 5
// 358.760 us; speedup vs baseline: 1.3457x; 1.0487x over previous
//
#include <hip/hip_runtime.h>
#include <hip/hip_bf16.h>

typedef unsigned short u16;
typedef u16 u16x8 __attribute__((ext_vector_type(8)));
typedef u16 u16x4 __attribute__((ext_vector_type(4)));
typedef __bf16 bf16x8 __attribute__((ext_vector_type(8)));
typedef float f32x4 __attribute__((ext_vector_type(4)));

__device__ __forceinline__ u16 f2bf(float f) {
  union { __hip_bfloat16 h; u16 u; } cv;
  cv.h = __float2bfloat16(f);
  return cv.u;
}
__device__ __forceinline__ float bf2f(u16 u) {
  union { unsigned u; float f; } c;
  c.u = ((unsigned)u) << 16;
  return c.f;
}

__device__ __forceinline__ void glds16(const void* g, void* l) {
  __builtin_amdgcn_global_load_lds(
      (const __attribute__((address_space(1))) unsigned int*)g,
      (__attribute__((address_space(3))) unsigned int*)l, 16, 0, 0);
}

// ---------------- transpose + fp32->bf16 convert:  W[K][N] -> Wt[N][K] ----------------
__global__ __launch_bounds__(256) void transpose_bf16(const float* __restrict__ W,
                                                      u16* __restrict__ Wt,
                                                      int K, int N) {
  __shared__ float tile[32][33];
  int tx = threadIdx.x, ty = threadIdx.y;
  int n0 = blockIdx.x * 32, k0 = blockIdx.y * 32;
#pragma unroll
  for (int j = 0; j < 4; ++j)
    tile[ty + j * 8][tx] = W[(size_t)(k0 + ty + j * 8) * N + n0 + tx];
  __syncthreads();
#pragma unroll
  for (int j = 0; j < 4; ++j)
    Wt[(size_t)(n0 + ty + j * 8) * K + k0 + tx] = f2bf(tile[tx][ty + j * 8]);
}

// four 1024x1024 transposes in one launch (z selects the weight)
__global__ __launch_bounds__(256) void transpose4(const float* __restrict__ W0,
                                                  const float* __restrict__ W1,
                                                  const float* __restrict__ W2,
                                                  const float* __restrict__ W3,
                                                  u16* __restrict__ T0, u16* __restrict__ T1,
                                                  u16* __restrict__ T2, u16* __restrict__ T3) {
  __shared__ float tile[32][33];
  int z = blockIdx.z;
  const float* W = (z == 0) ? W0 : (z == 1) ? W1 : (z == 2) ? W2 : W3;
  u16* T = (z == 0) ? T0 : (z == 1) ? T1 : (z == 2) ? T2 : T3;
  int tx = threadIdx.x, ty = threadIdx.y;
  int n0 = blockIdx.x * 32, k0 = blockIdx.y * 32;
#pragma unroll
  for (int j = 0; j < 4; ++j)
    tile[ty + j * 8][tx] = W[(size_t)(k0 + ty + j * 8) * 1024 + n0 + tx];
  __syncthreads();
#pragma unroll
  for (int j = 0; j < 4; ++j)
    T[(size_t)(n0 + ty + j * 8) * 1024 + k0 + tx] = f2bf(tile[tx][ty + j * 8]);
}

// ---------------- LayerNorm: fp32 in [rows][1024] -> bf16 out ----------------
__global__ __launch_bounds__(256) void ln_kernel(const float* __restrict__ x,
                                                 const float* __restrict__ w,
                                                 const float* __restrict__ b,
                                                 u16* __restrict__ out) {
  int row = blockIdx.x, t = threadIdx.x;
  const float* xr = x + (size_t)row * 1024;
  float4 v = *reinterpret_cast<const float4*>(xr + t * 4);
  float s = v.x + v.y + v.z + v.w;
  float s2 = v.x * v.x + v.y * v.y + v.z * v.z + v.w * v.w;
#pragma unroll
  for (int m = 1; m < 64; m <<= 1) {
    s += __shfl_xor(s, m, 64);
    s2 += __shfl_xor(s2, m, 64);
  }
  __shared__ float red[8];
  if ((t & 63) == 0) { red[t >> 6] = s; red[(t >> 6) + 4] = s2; }
  __syncthreads();
  s = red[0] + red[1] + red[2] + red[3];
  s2 = red[4] + red[5] + red[6] + red[7];
  float mu = s * (1.f / 1024.f);
  float var = s2 * (1.f / 1024.f) - mu * mu;
  float rs = rsqrtf(var + 1e-5f);
  float4 wv = *reinterpret_cast<const float4*>(w + t * 4);
  float4 bv = *reinterpret_cast<const float4*>(b + t * 4);
  u16x4 o;
  o.x = f2bf((v.x - mu) * rs * wv.x + bv.x);
  o.y = f2bf((v.y - mu) * rs * wv.y + bv.y);
  o.z = f2bf((v.z - mu) * rs * wv.z + bv.z);
  o.w = f2bf((v.w - mu) * rs * wv.w + bv.w);
  *reinterpret_cast<u16x4*>(out + (size_t)row * 1024 + t * 4) = o;
}

// ================= 256x256 8-phase MFMA GEMM (T1+T2+T3+T4+T5) =================
// MODE 0: QKV scatter (q pre-scaled). MODE 2: bf16 gelu(acc+bias). MODE 3: bf16 raw
// partials, dst selected by zt from {o0,o1,o2,o3}.
template <int MODE>
__global__ __launch_bounds__(512, 2) void gemm256(
    const u16* __restrict__ A, const u16* __restrict__ Bt,
    const float* __restrict__ b0, const float* __restrict__ b1,
    const float* __restrict__ b2,
    u16* __restrict__ o0, u16* __restrict__ o1, u16* __restrict__ o2,
    u16* __restrict__ o3,
    int Kfull, int KL, int MT, int NT, float qscale) {
  __shared__ u16 lds[2][2][2][256 * 32];  // [buf][op A0/B1][khalf][256 rows x 32 cols]
  const int tid = threadIdx.x;
  const int lane = tid & 63, w = tid >> 6;
  const int wm = w >> 2, wn = w & 3;
  const int l15 = lane & 15, l4 = lane >> 4;
  const int skey = (l15 >> 1) & 3;

  const int nwg = gridDim.x;
  int wg = (int)blockIdx.x;
  wg = (wg & 7) * (nwg >> 3) + (wg >> 3);
  const int mt = wg % MT;
  int rest = wg / MT;
  const int nt = rest % NT;
  const int zt = rest / NT;

  const int row0 = mt * 256, col0 = nt * 256;
  const int kbase = zt * KL;
  const int nkt = KL >> 6;

  auto stage = [&](int buf, int op, int ks, int kt) {
    const u16* src = op ? Bt : A;
    const int base = op ? col0 : row0;
    const int kb = kbase + (kt << 6) + (ks << 5);
    u16* dst = &lds[buf][op][ks][0];
#pragma unroll
    for (int i = 0; i < 2; ++i) {
      int c = i * 512 + tid;
      int r = c >> 2, ch = c & 3;
      int sch = ch ^ ((r >> 1) & 3);
      glds16(src + (size_t)(base + r) * Kfull + kb + sch * 8, dst + c * 8);
    }
  };
  auto rdA = [&](int buf, int ks, int m) -> bf16x8 {
    int row = wm * 128 + m * 16 + l15;
    return *reinterpret_cast<const bf16x8*>(&lds[buf][0][ks][row * 32 + ((l4 ^ skey) << 3)]);
  };
  auto rdB = [&](int buf, int ks, int n) -> bf16x8 {
    int row = wn * 64 + n * 16 + l15;
    return *reinterpret_cast<const bf16x8*>(&lds[buf][1][ks][row * 32 + ((l4 ^ skey) << 3)]);
  };

  f32x4 acc[8][4];
#pragma unroll
  for (int m = 0; m < 8; ++m)
#pragma unroll
    for (int n = 0; n < 4; ++n) acc[m][n] = (f32x4){0.f, 0.f, 0.f, 0.f};

  stage(0, 0, 0, 0);
  stage(0, 0, 1, 0);
  stage(0, 1, 0, 0);
  stage(0, 1, 1, 0);
  asm volatile("s_waitcnt vmcnt(2)" ::: "memory");
  __builtin_amdgcn_s_barrier();

  bf16x8 af[8];
  for (int t = 0; t < nkt; ++t) {
    const int cur = t & 1, nxt = cur ^ 1;
    const bool pf = (t + 1 < nkt);
    // ---- p0: ks0, n-half 0 ----
    {
#pragma unroll
      for (int m = 0; m < 8; ++m) af[m] = rdA(cur, 0, m);
      bf16x8 bq0 = rdB(cur, 0, 0), bq1 = rdB(cur, 0, 1);
      if (pf) stage(nxt, 0, 0, t + 1);
      __builtin_amdgcn_s_barrier();
      __builtin_amdgcn_s_setprio(1);
#pragma unroll
      for (int m = 0; m < 8; ++m) {
        acc[m][0] = __builtin_amdgcn_mfma_f32_16x16x32_bf16(af[m], bq0, acc[m][0], 0, 0, 0);
        acc[m][1] = __builtin_amdgcn_mfma_f32_16x16x32_bf16(af[m], bq1, acc[m][1], 0, 0, 0);
      }
      __builtin_amdgcn_s_setprio(0);
      __builtin_amdgcn_s_barrier();
    }
    // ---- p1: ks0, n-half 1 ----
    {
      bf16x8 bq2 = rdB(cur, 0, 2), bq3 = rdB(cur, 0, 3);
      if (pf) {
        stage(nxt, 0, 1, t + 1);
        asm volatile("s_waitcnt vmcnt(4)" ::: "memory");
      } else {
        asm volatile("s_waitcnt vmcnt(0)" ::: "memory");
      }
      __builtin_amdgcn_s_barrier();
      __builtin_amdgcn_s_setprio(1);
#pragma unroll
      for (int m = 0; m < 8; ++m) {
        acc[m][2] = __builtin_amdgcn_mfma_f32_16x16x32_bf16(af[m], bq2, acc[m][2], 0, 0, 0);
        acc[m][3] = __builtin_amdgcn_mfma_f32_16x16x32_bf16(af[m], bq3, acc[m][3], 0, 0, 0);
      }
      __builtin_amdgcn_s_setprio(0);
      __builtin_amdgcn_s_barrier();
    }
    // ---- p2: ks1, n-half 0 ----
    {
#pragma unroll
      for (int m = 0; m < 8; ++m) af[m] = rdA(cur, 1, m);
      bf16x8 bq0 = rdB(cur, 1, 0), bq1 = rdB(cur, 1, 1);
      if (pf) stage(nxt, 1, 0, t + 1);
      __builtin_amdgcn_s_barrier();
      __builtin_amdgcn_s_setprio(1);
#pragma unroll
      for (int m = 0; m < 8; ++m) {
        acc[m][0] = __builtin_amdgcn_mfma_f32_16x16x32_bf16(af[m], bq0, acc[m][0], 0, 0, 0);
        acc[m][1] = __builtin_amdgcn_mfma_f32_16x16x32_bf16(af[m], bq1, acc[m][1], 0, 0, 0);
      }
      __builtin_amdgcn_s_setprio(0);
      __builtin_amdgcn_s_barrier();
    }
    // ---- p3: ks1, n-half 1 ----
    {
      bf16x8 bq2 = rdB(cur, 1, 2), bq3 = rdB(cur, 1, 3);
      if (pf) stage(nxt, 1, 1, t + 1);
      asm volatile("s_waitcnt vmcnt(2)" ::: "memory");
      __builtin_amdgcn_s_barrier();
      __builtin_amdgcn_s_setprio(1);
#pragma unroll
      for (int m = 0; m < 8; ++m) {
        acc[m][2] = __builtin_amdgcn_mfma_f32_16x16x32_bf16(af[m], bq2, acc[m][2], 0, 0, 0);
        acc[m][3] = __builtin_amdgcn_mfma_f32_16x16x32_bf16(af[m], bq3, acc[m][3], 0, 0, 0);
      }
      __builtin_amdgcn_s_setprio(0);
      __builtin_amdgcn_s_barrier();
    }
  }

  // ---------------- epilogue ----------------
  if constexpr (MODE == 0) {
    const int which = nt >> 2;   // 0=Q,1=K,2=V
    const int bidx = mt >> 2;    // batch
#pragma unroll
    for (int m = 0; m < 8; ++m)
#pragma unroll
      for (int n = 0; n < 4; ++n) {
        int colc = (col0 & 1023) + wn * 64 + n * 16 + l15;
        int hh = colc >> 6, d = colc & 63;
        int nb = (row0 & 1023) + wm * 128 + m * 16 + l4 * 4;
        if (which == 2) {
          u16x4 pk;
#pragma unroll
          for (int r = 0; r < 4; ++r) pk[r] = f2bf(acc[m][n][r] + b2[colc]);
          *reinterpret_cast<u16x4*>(o2 + (((size_t)(bidx * 16 + hh) * 64 + d) * 1024 + nb)) = pk;
        } else {
          const float* bb = (which == 0) ? b0 : b1;
          u16* dst = (which == 0) ? o0 : o1;
          float sc = (which == 0) ? qscale : 1.0f;
#pragma unroll
          for (int r = 0; r < 4; ++r)
            dst[((size_t)(bidx * 16 + hh) * 1024 + nb + r) * 64 + d] =
                f2bf((acc[m][n][r] + bb[colc]) * sc);
        }
      }
  } else if constexpr (MODE == 2) {
    const int N = NT * 256;
#pragma unroll
    for (int m = 0; m < 8; ++m)
#pragma unroll
      for (int n = 0; n < 4; ++n)
#pragma unroll
        for (int r = 0; r < 4; ++r) {
          int row = row0 + wm * 128 + m * 16 + l4 * 4 + r;
          int col = col0 + wn * 64 + n * 16 + l15;
          float val = acc[m][n][r] + b0[col];
          float g = 0.5f * val * (1.0f + erff(val * 0.70710678118f));
          o0[(size_t)row * N + col] = f2bf(g);
        }
  } else {  // MODE 3: raw bf16 partials, buffer selected by zt
    const int N = NT * 256;
    u16* base = (zt == 0) ? o0 : (zt == 1) ? o1 : (zt == 2) ? o2 : o3;
#pragma unroll
    for (int m = 0; m < 8; ++m)
#pragma unroll
      for (int n = 0; n < 4; ++n)
#pragma unroll
        for (int r = 0; r < 4; ++r) {
          int row = row0 + wm * 128 + m * 16 + l4 * 4 + r;
          int col = col0 + wn * 64 + n * 16 + l15;
          base[(size_t)row * N + col] = f2bf(acc[m][n][r]);
        }
  }
}

// ---------------- split-K reduce: out = p0+p1+p2+p3 + bias + res (N=1024 cols) -------
__global__ __launch_bounds__(256) void reduce4(const u16* __restrict__ p0,
                                               const u16* __restrict__ p1,
                                               const u16* __restrict__ p2,
                                               const u16* __restrict__ p3,
                                               const float* __restrict__ bias,
                                               const float* __restrict__ res,
                                               float* __restrict__ out) {
  size_t i = ((size_t)blockIdx.x * 256 + threadIdx.x) * 8;
  int col = (int)(i & 1023);
  float s[8];
  float4 r0 = *reinterpret_cast<const float4*>(res + i);
  float4 r1 = *reinterpret_cast<const float4*>(res + i + 4);
  s[0] = r0.x; s[1] = r0.y; s[2] = r0.z; s[3] = r0.w;
  s[4] = r1.x; s[5] = r1.y; s[6] = r1.z; s[7] = r1.w;
#pragma unroll
  for (int j = 0; j < 8; ++j) s[j] += bias[col + j];
  const u16* ps[4] = {p0, p1, p2, p3};
#pragma unroll
  for (int sp = 0; sp < 4; ++sp) {
    u16x8 pv = *reinterpret_cast<const u16x8*>(ps[sp] + i);
#pragma unroll
    for (int j = 0; j < 8; ++j) s[j] += bf2f(pv[j]);
  }
  float4 o0 = {s[0], s[1], s[2], s[3]};
  float4 o1 = {s[4], s[5], s[6], s[7]};
  *reinterpret_cast<float4*>(out + i) = o0;
  *reinterpret_cast<float4*>(out + i + 4) = o1;
}

// ---------------- fused flash attention, swapped-operand softmax ----------------
// q,k: [BH, N, 64] bf16 (q pre-scaled by 0.125*log2e); vt: [BH, 64, N] bf16
// S^T = mfma(K,Q): each lane owns one q-row -> lane-local softmax (2 shuffles).
// O^T = mfma(V^T, P^T). out o: [B, N, 1024] bf16.
__global__ __launch_bounds__(256) void attn_kernel(const u16* __restrict__ q,
                                                   const u16* __restrict__ k,
                                                   const u16* __restrict__ vt,
                                                   u16* __restrict__ o) {
  const int bh = blockIdx.x, qb = blockIdx.y;
  const int b = bh >> 4, h = bh & 15;
  __shared__ u16 Ks[2][4096];
  __shared__ u16 Vt[2][4096];
  __shared__ u16 Ps[4][1024];
  const int tid = threadIdx.x, lane = tid & 63, w = tid >> 6;
  const int l15 = lane & 15, l4 = lane >> 4;
  const int sw = l15 & 7;
  const u16* kbase = k + (size_t)bh * 65536;
  const u16* vtbase = vt + (size_t)bh * 65536;

  // Q B-fragment straight from global: Q[q=w*16+l15][kd=l4*8..]
  const u16* qrow = q + ((size_t)bh * 1024 + qb * 64 + w * 16 + l15) * 64;
  bf16x8 qf0 = *reinterpret_cast<const bf16x8*>(qrow + l4 * 8);
  bf16x8 qf1 = *reinterpret_cast<const bf16x8*>(qrow + 32 + l4 * 8);

  auto stageKV = [&](int buf, int kv0) {
#pragma unroll
    for (int i = 0; i < 2; ++i) {
      int c = i * 256 + tid, r = c >> 3, sl = (c & 7) ^ (r & 7);
      glds16(kbase + (size_t)(kv0 + r) * 64 + sl * 8, &Ks[buf][c * 8]);
    }
#pragma unroll
    for (int i = 0; i < 2; ++i) {
      int c = i * 256 + tid, r = c >> 3, sl = (c & 7) ^ (r & 7);
      glds16(vtbase + (size_t)r * 1024 + kv0 + sl * 8, &Vt[buf][c * 8]);
    }
  };

  f32x4 oacc[4];  // O^T: oacc[n][r] = O^T[d = n*16 + l4*4 + r][q = w*16+l15]
#pragma unroll
  for (int n = 0; n < 4; ++n) oacc[n] = (f32x4){0.f, 0.f, 0.f, 0.f};
  float mrow = -3.0e38f, lrow = 0.f;  // per-lane scalars (one q-row per lane)

  stageKV(0, 0);
  __syncthreads();

  for (int kv0 = 0; kv0 < 1024; kv0 += 64) {
    int cur = (kv0 >> 6) & 1;
    if (kv0 + 64 < 1024) stageKV(cur ^ 1, kv0 + 64);

    // S^T[k][q]: st[t][r] = S[k = t*16 + l4*4 + r][q = l15]
    f32x4 st[4];
#pragma unroll
    for (int t = 0; t < 4; ++t) {
      int row = t * 16 + l15;
      f32x4 s = (f32x4){0.f, 0.f, 0.f, 0.f};
      bf16x8 kf0 = *reinterpret_cast<const bf16x8*>(&Ks[cur][row * 64 + ((l4 ^ sw) << 3)]);
      s = __builtin_amdgcn_mfma_f32_16x16x32_bf16(kf0, qf0, s, 0, 0, 0);
      bf16x8 kf1 = *reinterpret_cast<const bf16x8*>(&Ks[cur][row * 64 + (((4 + l4) ^ sw) << 3)]);
      s = __builtin_amdgcn_mfma_f32_16x16x32_bf16(kf1, qf1, s, 0, 0, 0);
      st[t] = s;
    }

    // lane-local softmax over the 16 values + 2 shuffles (lanes l15+{0,16,32,48})
    float tm = st[0][0];
#pragma unroll
    for (int t = 0; t < 4; ++t)
#pragma unroll
      for (int r = 0; r < 4; ++r) tm = fmaxf(tm, st[t][r]);
    tm = fmaxf(tm, __shfl_xor(tm, 16, 64));
    tm = fmaxf(tm, __shfl_xor(tm, 32, 64));
    if (!__all(tm - mrow <= 8.f)) {  // defer-max (T13): skip rescale when growth small
      float mnew = fmaxf(mrow, tm);
      float al = exp2f(mrow - mnew);
      lrow *= al;
#pragma unroll
      for (int n = 0; n < 4; ++n)
#pragma unroll
        for (int r = 0; r < 4; ++r) oacc[n][r] *= al;
      mrow = mnew;
    }
    float pr[4][4];
    float ps = 0.f;
#pragma unroll
    for (int t = 0; t < 4; ++t)
#pragma unroll
      for (int r = 0; r < 4; ++r) {
        pr[t][r] = exp2f(st[t][r] - mrow);
        ps += pr[t][r];
      }
    ps += __shfl_xor(ps, 16, 64);
    ps += __shfl_xor(ps, 32, 64);
    lrow += ps;

    // pack P: row q=l15, k-run of 4 at k0 = t*16 + l4*4 -> one b64 write per t
#pragma unroll
    for (int t = 0; t < 4; ++t) {
      u16x4 pk;
#pragma unroll
      for (int r = 0; r < 4; ++r) pk[r] = f2bf(pr[t][r]);
      int swch = ((t << 1) | (l4 >> 1)) ^ sw;
      *reinterpret_cast<u16x4*>(&Ps[w][l15 * 64 + swch * 8 + (l4 & 1) * 4]) = pk;
    }

    // O^T += V^T * P^T
#pragma unroll
    for (int c2 = 0; c2 < 2; ++c2) {
      bf16x8 pf = *reinterpret_cast<const bf16x8*>(
          &Ps[w][l15 * 64 + ((((c2 << 2) | l4) ^ sw) << 3)]);
#pragma unroll
      for (int n = 0; n < 4; ++n) {
        bf16x8 vf = *reinterpret_cast<const bf16x8*>(
            &Vt[cur][(n * 16 + l15) * 64 + ((((c2 << 2) | l4) ^ sw) << 3)]);
        oacc[n] = __builtin_amdgcn_mfma_f32_16x16x32_bf16(vf, pf, oacc[n], 0, 0, 0);
      }
    }
    __syncthreads();
  }

  float inv = 1.0f / lrow;
  int nr = qb * 64 + w * 16 + l15;
#pragma unroll
  for (int n = 0; n < 4; ++n) {
    u16x4 pk;
#pragma unroll
    for (int r = 0; r < 4; ++r) pk[r] = f2bf(oacc[n][r] * inv);
    *reinterpret_cast<u16x4*>(
        o + ((size_t)(b * 1024 + nr)) * 1024 + h * 64 + n * 16 + l4 * 4) = pk;
  }
}

extern "C" void kernel_launch(void* const* d_in, const int* in_sizes, int n_in,
                              void* d_out, int out_size, void* d_ws, size_t ws_size,
                              hipStream_t stream) {
  (void)in_sizes; (void)n_in; (void)out_size; (void)ws_size;
  const float* x     = (const float*)d_in[0];
  const float* ln1w  = (const float*)d_in[1];
  const float* ln1b  = (const float*)d_in[2];
  const float* Wq    = (const float*)d_in[3];
  const float* bq    = (const float*)d_in[4];
  const float* Wk    = (const float*)d_in[5];
  const float* bk    = (const float*)d_in[6];
  const float* Wv    = (const float*)d_in[7];
  const float* bv    = (const float*)d_in[8];
  const float* Wo    = (const float*)d_in[9];
  const float* bo    = (const float*)d_in[10];
  const float* ln2w  = (const float*)d_in[11];
  const float* ln2b  = (const float*)d_in[12];
  const float* Wfc   = (const float*)d_in[13];
  const float* bfc   = (const float*)d_in[14];
  const float* Wproj = (const float*)d_in[15];
  const float* bproj = (const float*)d_in[16];
  float* out = (float*)d_out;

  char* p = (char*)d_ws;
  u16* hb     = (u16*)p; p += (size_t)4096 * 1024 * 2;   // LN1 out bf16
  u16* WqkvT  = (u16*)p; p += (size_t)3072 * 1024 * 2;
  u16* WoT    = (u16*)p; p += (size_t)1024 * 1024 * 2;
  u16* WfcT   = (u16*)p; p += (size_t)4096 * 1024 * 2;
  u16* WprojT = (u16*)p; p += (size_t)1024 * 4096 * 2;
  u16* qb_    = (u16*)p; p += (size_t)4096 * 1024 * 2;   // q; also split-K partial 0
  u16* kb_    = (u16*)p; p += (size_t)4096 * 1024 * 2;   // k; partial 1
  u16* vt_    = (u16*)p; p += (size_t)4096 * 1024 * 2;   // V^T; partial 2
  u16* ob_    = (u16*)p; p += (size_t)4096 * 1024 * 2;   // attn out; Proj partial 3
  float* x1   = (float*)p; p += (size_t)4096 * 1024 * 4; // residual 1 fp32
  u16* h2     = (u16*)p; p += (size_t)4096 * 1024 * 2;   // Wo partial 3; then LN2 out
  u16* ffnb   = (u16*)p; p += (size_t)4096 * 4096 * 2;   // gelu out bf16

  const float qscale = 0.125f * 1.44269504089f;  // 1/sqrt(64) * log2(e)

  dim3 tb(32, 8);
  transpose4<<<dim3(32, 32, 4), tb, 0, stream>>>(Wq, Wk, Wv, Wo,
                                                 WqkvT, WqkvT + (size_t)1024 * 1024,
                                                 WqkvT + (size_t)2048 * 1024, WoT);
  transpose_bf16<<<dim3(128, 32), tb, 0, stream>>>(Wfc, WfcT, 1024, 4096);
  transpose_bf16<<<dim3(32, 128), tb, 0, stream>>>(Wproj, WprojT, 4096, 1024);

  ln_kernel<<<4096, 256, 0, stream>>>(x, ln1w, ln1b, hb);

  // QKV: M=4096, N=3072, K=1024 -> 16x12 = 192 blocks
  gemm256<0><<<192, 512, 0, stream>>>(hb, WqkvT, bq, bk, bv,
                                      qb_, kb_, vt_, nullptr, 1024, 1024, 16, 12, qscale);

  attn_kernel<<<dim3(64, 16), 256, 0, stream>>>(qb_, kb_, vt_, ob_);

  // Wo: M=4096, N=1024, K=1024, split-K=4 (KL=256) -> 256 blocks; partials qb_,kb_,vt_,h2
  gemm256<3><<<256, 512, 0, stream>>>(ob_, WoT, nullptr, nullptr, nullptr,
                                      qb_, kb_, vt_, h2, 1024, 256, 16, 4, 1.f);
  reduce4<<<2048, 256, 0, stream>>>(qb_, kb_, vt_, h2, bo, x, x1);

  ln_kernel<<<4096, 256, 0, stream>>>(x1, ln2w, ln2b, h2);

  // FC: M=4096, N=4096, K=1024 -> 256 blocks
  gemm256<2><<<256, 512, 0, stream>>>(h2, WfcT, bfc, nullptr, nullptr,
                                      ffnb, nullptr, nullptr, nullptr, 1024, 1024, 16, 16, 1.f);

  // Proj: M=4096, N=1024, K=4096, split-K=4 (KL=1024) -> 256 blocks; partials qb_..ob_
  gemm256<3><<<256, 512, 0, stream>>>(ffnb, WprojT, nullptr, nullptr, nullptr,
                                      qb_, kb_, vt_, ob_, 4096, 1024, 16, 4, 1.f);
  reduce4<<<2048, 256, 0, stream>>>(qb_, kb_, vt_, ob_, bproj, x1, out);
}